// Round 4
// baseline (423.298 us; speedup 1.0000x reference)
//
#include <hip/hip_runtime.h>
#include <hip/hip_bf16.h>

typedef __attribute__((ext_vector_type(4))) float f32x4;
typedef __attribute__((ext_vector_type(8))) short short8;

static constexpr int BB = 32;
static constexpr int SEQ = 1024;
static constexpr int DIM = 1024;

__device__ __forceinline__ ushort f2bf(float f) {
  union { float f; uint u; } x; x.f = f;
  uint r = x.u + 0x7fffu + ((x.u >> 16) & 1u);
  return (ushort)(r >> 16);
}
__device__ __forceinline__ float bf2f(ushort h) {
  union { uint u; float f; } x; x.u = ((uint)h) << 16; return x.f;
}

// async global->LDS, 16B per lane. Per-lane global src; LDS dest must be
// wave-uniform base + lane*16 (our addressing satisfies this).
__device__ __forceinline__ void async16(const void* g, void* l) {
  __builtin_amdgcn_global_load_lds(
      (const __attribute__((address_space(1))) unsigned int*)g,
      (__attribute__((address_space(3))) unsigned int*)l, 16, 0, 0);
}

#define SCHED0 __builtin_amdgcn_sched_barrier(0)
#define BAR    __builtin_amdgcn_s_barrier()

// fp32 -> bf16 elementwise (vectorized by 4)
__global__ void cvt_kernel(const float* __restrict__ in, ushort* __restrict__ out, long n4) {
  long i = (long)blockIdx.x * blockDim.x + threadIdx.x;
  const long stride = (long)gridDim.x * blockDim.x;
  for (; i < n4; i += stride) {
    float4 v = reinterpret_cast<const float4*>(in)[i];
    ushort4 o = make_ushort4(f2bf(v.x), f2bf(v.y), f2bf(v.z), f2bf(v.w));
    reinterpret_cast<ushort4*>(out)[i] = o;
  }
}

// ---------------------------------------------------------------------------
// 256x256-tile, BK=64, 8-wave (2Mx4N), 4-window-per-K-tile GEMM.
// Each window: [stage global_load_lds for future tile] + [ds_read own subtile]
// + [MFMA quadrant] + barrier. No mid-window barrier/drain: frag reads are
// plain loads, so the compiler emits per-use lgkmcnt waits and overlaps the
// reads with the MFMA cluster inside the window. vmcnt(6) once per K-tile.
// C[m,n] = scale * sum_k A[m,k]*Bt[n,k] (+ bias[n]); A:[M][K] Bt:[N][K] bf16.
// LDS rows remapped so each 64-row staging chunk is contiguous:
//   A lds row r: block row = ((r>>6)&1)*128 + (r>>7)*64 + (r&63)   (mh-major)
//   B lds row r: block col = ((r>>5)&3)*64 + (r>>7)*32 + (r&31)    (nh-major)
// Swizzle (G4): byte ^= ((row&7)<<4) — inverse-applied on the global source
// (LDS dest of global_load_lds stays linear) and on the ds_read address.
// TMODE=1: additionally write transposed bf16 output to Tout[z2][col][row].
// ---------------------------------------------------------------------------
template<int OUT_BF16, int HAS_BIAS, int TMODE>
__global__ __launch_bounds__(512, 2)
void gemm256(const ushort* __restrict__ A, const ushort* __restrict__ Bt,
             void* __restrict__ Cv, const float* __restrict__ bias,
             ushort* __restrict__ Tout,
             int M, int N, int K, float scale,
             long sA, long sB, long sC)
{
  __shared__ __align__(16) ushort As[2][16384];
  __shared__ __align__(16) ushort Bs[2][16384];

  const int t = threadIdx.x;
  const int z = blockIdx.z;
  const ushort* Ab = A + (long)z * sA;
  const ushort* Bb = Bt + (long)z * sB;
  const int tm = blockIdx.y * 256;
  const int tn = blockIdx.x * 256;

  const int l    = t & 63;
  const int w    = t >> 6;
  const int wrow = w >> 2;       // 0..1
  const int wcol = w & 3;        // 0..3
  const int fr   = l & 15;
  const int g    = l >> 4;       // k-group 0..3
  const int aflip = (fr & 7) << 4;  // G4 swizzle XOR for frag reads

  f32x4 acc[8][4];
#pragma unroll
  for (int i = 0; i < 8; ++i)
#pragma unroll
    for (int j = 0; j < 4; ++j) acc[i][j] = {0.f, 0.f, 0.f, 0.f};

  short8 a[4][2], b0[2][2], b1[2][2];

  // --- staging: one call = 512 threads x 16B = 8KB = 64 LDS rows ---
  auto stageA = [&](int buf, int R0, int k0) {
    const int P = (R0 << 7) + (t << 4);            // physical LDS byte
    const int L = P ^ (((P >> 7) & 7) << 4);       // logical byte (involution)
    const int lr = L >> 7;
    const int kb = (L & 127) >> 1;
    const int brow = ((lr >> 6) & 1) * 128 + ((lr >> 7) << 6) + (lr & 63);
    async16(Ab + (long)(tm + brow) * K + (k0 + kb), &As[buf][P >> 1]);
  };
  auto stageB = [&](int buf, int R0, int k0) {
    const int P = (R0 << 7) + (t << 4);
    const int L = P ^ (((P >> 7) & 7) << 4);
    const int lr = L >> 7;
    const int kb = (L & 127) >> 1;
    const int bcol = ((lr >> 5) & 3) * 64 + ((lr >> 7) << 5) + (lr & 31);
    async16(Bb + (long)(tn + bcol) * K + (k0 + kb), &Bs[buf][P >> 1]);
  };

  // --- swizzled fragment reads (row&7 == fr&7 for all frag bases) ---
  auto ldA = [&](int buf, int mh, int mi, int ks) -> short8 {
    const int off = (((mh << 7) + (wrow << 6) + (mi << 4) + fr) << 7) + (ks << 6) + (g << 4);
    return *(const short8*)((const char*)As + (buf << 15) + (off ^ aflip));
  };
  auto ldB = [&](int buf, int nh, int ni, int ks) -> short8 {
    const int off = (((nh << 7) + (wcol << 5) + (ni << 4) + fr) << 7) + (ks << 6) + (g << 4);
    return *(const short8*)((const char*)Bs + (buf << 15) + (off ^ aflip));
  };

  const int NKT = K >> 6;  // >= 2 here (K=1024)

  // --- prologue: kt0 fully (8 loads), kt1 A-a,B-0,B-1 (6 loads) ---
  stageA(0, 0, 0);  stageA(0, 64, 0);
  stageB(0, 0, 0);  stageB(0, 64, 0);
  stageB(0, 128, 0); stageB(0, 192, 0);
  stageA(0, 128, 0); stageA(0, 192, 0);
  if (NKT > 1) {
    stageA(1, 0, 64);  stageA(1, 64, 64);
    stageB(1, 0, 64);  stageB(1, 64, 64);
    stageB(1, 128, 64); stageB(1, 192, 64);
    asm volatile("s_waitcnt vmcnt(6)" ::: "memory");
  } else {
    asm volatile("s_waitcnt vmcnt(0)" ::: "memory");
  }
  SCHED0; BAR;

  for (int kt = 0; kt < NKT; ++kt) {
    const int buf = kt & 1;
    const int k1 = (kt + 1) << 6;
    const int k2 = (kt + 2) << 6;
    const bool s1 = (kt + 1) < NKT;
    const bool s2 = (kt + 2) < NKT;

    // ---- W0: stage A-b of kt+1 (other buf); read A(mh0)+B(nh0); MFMA Q0
    if (s1) { stageA(buf ^ 1, 128, k1); stageA(buf ^ 1, 192, k1); }
#pragma unroll
    for (int mi = 0; mi < 4; ++mi) {
      a[mi][0] = ldA(buf, 0, mi, 0);
      a[mi][1] = ldA(buf, 0, mi, 1);
    }
#pragma unroll
    for (int ni = 0; ni < 2; ++ni) {
      b0[ni][0] = ldB(buf, 0, ni, 0);
      b0[ni][1] = ldB(buf, 0, ni, 1);
    }
    __builtin_amdgcn_s_setprio(1);
#pragma unroll
    for (int ks = 0; ks < 2; ++ks)
#pragma unroll
      for (int mi = 0; mi < 4; ++mi)
#pragma unroll
        for (int ni = 0; ni < 2; ++ni)
          acc[mi][ni] = __builtin_amdgcn_mfma_f32_16x16x32_bf16(
              a[mi][ks], b0[ni][ks], acc[mi][ni], 0, 0, 0);
    __builtin_amdgcn_s_setprio(0);
    BAR;

    // ---- W1: stage A-a of kt+2 (cur buf, dead after W0); read B(nh1); MFMA Q1
    if (s2) { stageA(buf, 0, k2); stageA(buf, 64, k2); }
#pragma unroll
    for (int ni = 0; ni < 2; ++ni) {
      b1[ni][0] = ldB(buf, 1, ni, 0);
      b1[ni][1] = ldB(buf, 1, ni, 1);
    }
    __builtin_amdgcn_s_setprio(1);
#pragma unroll
    for (int ks = 0; ks < 2; ++ks)
#pragma unroll
      for (int mi = 0; mi < 4; ++mi)
#pragma unroll
        for (int ni = 0; ni < 2; ++ni)
          acc[mi][2 + ni] = __builtin_amdgcn_mfma_f32_16x16x32_bf16(
              a[mi][ks], b1[ni][ks], acc[mi][2 + ni], 0, 0, 0);
    __builtin_amdgcn_s_setprio(0);
    BAR;

    // ---- W2: stage B-0 of kt+2 (dead after W0); read A(mh1); MFMA Q2
    if (s2) { stageB(buf, 0, k2); stageB(buf, 64, k2); }
#pragma unroll
    for (int mi = 0; mi < 4; ++mi) {
      a[mi][0] = ldA(buf, 1, mi, 0);
      a[mi][1] = ldA(buf, 1, mi, 1);
    }
    __builtin_amdgcn_s_setprio(1);
#pragma unroll
    for (int ks = 0; ks < 2; ++ks)
#pragma unroll
      for (int mi = 0; mi < 4; ++mi)
#pragma unroll
        for (int ni = 0; ni < 2; ++ni)
          acc[4 + mi][ni] = __builtin_amdgcn_mfma_f32_16x16x32_bf16(
              a[mi][ks], b0[ni][ks], acc[4 + mi][ni], 0, 0, 0);
    __builtin_amdgcn_s_setprio(0);
    BAR;

    // ---- W3: stage B-1 of kt+2 (dead after W1); MFMA Q3; end-of-tile vmcnt
    if (s2) { stageB(buf, 128, k2); stageB(buf, 192, k2); }
    __builtin_amdgcn_s_setprio(1);
#pragma unroll
    for (int ks = 0; ks < 2; ++ks)
#pragma unroll
      for (int mi = 0; mi < 4; ++mi)
#pragma unroll
        for (int ni = 0; ni < 2; ++ni)
          acc[4 + mi][2 + ni] = __builtin_amdgcn_mfma_f32_16x16x32_bf16(
              a[mi][ks], b1[ni][ks], acc[4 + mi][2 + ni], 0, 0, 0);
    __builtin_amdgcn_s_setprio(0);
    if (kt < NKT - 2) {
      asm volatile("s_waitcnt vmcnt(6)" ::: "memory");   // kt+1 fully in LDS
    } else if (kt == NKT - 2) {
      asm volatile("s_waitcnt vmcnt(0)" ::: "memory");   // drain for last tile
    }
    BAR;
  }

  // --- epilogue: C/D layout col=lane&15, row=g*4+reg ---
  const int cr = g * 4;
#pragma unroll
  for (int mi = 0; mi < 8; ++mi) {
#pragma unroll
    for (int ni = 0; ni < 4; ++ni) {
      const int row = tm + wrow * 128 + mi * 16 + cr;
      const int col = tn + wcol * 64 + ni * 16 + fr;
      const float bv = HAS_BIAS ? bias[col] : 0.0f;
      float v[4];
#pragma unroll
      for (int r = 0; r < 4; ++r) v[r] = acc[mi][ni][r] * scale + bv;
#pragma unroll
      for (int r = 0; r < 4; ++r) {
        const long off = (long)z * sC + (long)(row + r) * N + col;
        if (OUT_BF16) ((ushort*)Cv)[off] = f2bf(v[r]);
        else          ((float*)Cv)[off]  = v[r];
      }
      if (TMODE) {  // transposed copy: Tout[z2][col][row..row+3], z2 = row>>10
        ushort4 o = make_ushort4(f2bf(v[0]), f2bf(v[1]), f2bf(v[2]), f2bf(v[3]));
        const long ti = ((long)(row >> 10) << 20) + ((long)col << 10) + (row & 1023);
        *(ushort4*)&Tout[ti] = o;
      }
    }
  }
}

// softmax over BATCH dim (axis=0): for each (q,k), normalize across 32 batches.
__global__ void softmax_b(ushort* __restrict__ sc) {
  const long SSl = (long)SEQ * SEQ;
  const long e = ((long)blockIdx.x * blockDim.x + threadIdx.x) * 4;
  if (e >= SSl) return;
  uint2 raw[BB];
#pragma unroll
  for (int b = 0; b < BB; ++b) raw[b] = *(const uint2*)&sc[b * SSl + e];
  float mx[4] = {-3.0e38f, -3.0e38f, -3.0e38f, -3.0e38f};
#pragma unroll
  for (int b = 0; b < BB; ++b) {
    const uint lo = raw[b].x, hi = raw[b].y;
    mx[0] = fmaxf(mx[0], bf2f((ushort)(lo & 0xffffu)));
    mx[1] = fmaxf(mx[1], bf2f((ushort)(lo >> 16)));
    mx[2] = fmaxf(mx[2], bf2f((ushort)(hi & 0xffffu)));
    mx[3] = fmaxf(mx[3], bf2f((ushort)(hi >> 16)));
  }
  float sum[4] = {0.f, 0.f, 0.f, 0.f};
#pragma unroll
  for (int b = 0; b < BB; ++b) {
    const uint lo = raw[b].x, hi = raw[b].y;
    const float x0 = __expf(bf2f((ushort)(lo & 0xffffu)) - mx[0]);
    const float x1 = __expf(bf2f((ushort)(lo >> 16))     - mx[1]);
    const float x2 = __expf(bf2f((ushort)(hi & 0xffffu)) - mx[2]);
    const float x3 = __expf(bf2f((ushort)(hi >> 16))     - mx[3]);
    sum[0] += x0; sum[1] += x1; sum[2] += x2; sum[3] += x3;
    raw[b].x = (uint)f2bf(x0) | ((uint)f2bf(x1) << 16);
    raw[b].y = (uint)f2bf(x2) | ((uint)f2bf(x3) << 16);
  }
  const float r0 = 1.0f / sum[0], r1 = 1.0f / sum[1];
  const float r2 = 1.0f / sum[2], r3 = 1.0f / sum[3];
#pragma unroll
  for (int b = 0; b < BB; ++b) {
    const uint lo = raw[b].x, hi = raw[b].y;
    const uint o0 = f2bf(bf2f((ushort)(lo & 0xffffu)) * r0);
    const uint o1 = f2bf(bf2f((ushort)(lo >> 16))     * r1);
    const uint o2 = f2bf(bf2f((ushort)(hi & 0xffffu)) * r2);
    const uint o3 = f2bf(bf2f((ushort)(hi >> 16))     * r3);
    uint2 o; o.x = o0 | (o1 << 16); o.y = o2 | (o3 << 16);
    *(uint2*)&sc[b * SSl + e] = o;
  }
}

extern "C" void kernel_launch(void* const* d_in, const int* in_sizes, int n_in,
                              void* d_out, int out_size, void* d_ws, size_t ws_size,
                              hipStream_t stream) {
  const float* text = (const float*)d_in[0];
  const float* W    = (const float*)d_in[1];
  const float* bias = (const float*)d_in[2];
  float* out = (float*)d_out;

  const long nTxt = (long)BB * SEQ * DIM;   // 33,554,432
  const long nW   = (long)DIM * DIM;        // 1,048,576
  const long SSl  = (long)SEQ * SEQ;        // per-batch score elems

  char* ws = (char*)d_ws;
  ushort* qkv   = (ushort*)ws;                 // 64MB bf16 qkv [B][S][D]
  ushort* qkvT  = (ushort*)(ws + nTxt * 2);    // 64MB bf16 qkv^T [B][D][S]
  ushort* sc    = (ushort*)(ws + nTxt * 4);    // 64MB: text_bf16, then scores/attn
  ushort* textb = sc;                          // alias (text_bf16 dead after GEMM1)
  ushort* Wb    = (ushort*)(ws + nTxt * 6);    // 2MB bf16 W [D][D]
  if (ws_size < (size_t)(nTxt * 6 + nW * 2)) return;  // insufficient scratch

  // 1. convert inputs to bf16
  cvt_kernel<<<2048, 256, 0, stream>>>(text, textb, nTxt / 4);
  cvt_kernel<<<256, 256, 0, stream>>>(W, Wb, nW / 4);
  // 2. qkv = text @ W.T + b  (M=32768,N=1024,K=1024); also writes qkvT fused
  gemm256<1, 1, 1><<<dim3(4, 128, 1), 512, 0, stream>>>(
      textb, Wb, qkv, bias, qkvT, BB * SEQ, DIM, DIM, 1.0f, 0, 0, 0);
  // 3. scores[b] = qkv[b] @ qkv[b]^T / sqrt(D), bf16 out
  gemm256<1, 0, 0><<<dim3(4, 4, BB), 512, 0, stream>>>(
      qkv, qkv, sc, nullptr, nullptr, SEQ, SEQ, DIM, 0.03125f, SSl, SSl, SSl);
  // 4. softmax over batch dim (in-place)
  softmax_b<<<1024, 256, 0, stream>>>(sc);
  // 5. out[b] = attn[b] @ qkv[b]  (B operand via qkvT), fp32 out
  gemm256<0, 0, 0><<<dim3(4, 4, BB), 512, 0, stream>>>(
      sc, qkvT, out, nullptr, nullptr, SEQ, DIM, SEQ, 1.0f, SSl, SSl, SSl);
}

// Round 5
// 376.335 us; speedup vs baseline: 1.1248x; 1.1248x over previous
//
#include <hip/hip_runtime.h>
#include <hip/hip_bf16.h>

typedef __attribute__((ext_vector_type(4))) float f32x4;
typedef __attribute__((ext_vector_type(8))) short short8;

static constexpr int BB = 32;
static constexpr int SEQ = 1024;
static constexpr int DIM = 1024;

__device__ __forceinline__ ushort f2bf(float f) {
  union { float f; uint u; } x; x.f = f;
  uint r = x.u + 0x7fffu + ((x.u >> 16) & 1u);
  return (ushort)(r >> 16);
}
__device__ __forceinline__ float bf2f(ushort h) {
  union { uint u; float f; } x; x.u = ((uint)h) << 16; return x.f;
}

// async global->LDS, 16B per lane (dest = wave-uniform base + lane*16).
__device__ __forceinline__ void async16(const void* g, void* l) {
  __builtin_amdgcn_global_load_lds(
      (const __attribute__((address_space(1))) unsigned int*)g,
      (__attribute__((address_space(3))) unsigned int*)l, 16, 0, 0);
}

#define SCHED0 __builtin_amdgcn_sched_barrier(0)
#define BAR    __builtin_amdgcn_s_barrier()
#define VM(n)  asm volatile("s_waitcnt vmcnt(" #n ")" ::: "memory")

// fp32 -> bf16 elementwise (vectorized by 4)
__global__ void cvt_kernel(const float* __restrict__ in, ushort* __restrict__ out, long n4) {
  long i = (long)blockIdx.x * blockDim.x + threadIdx.x;
  const long stride = (long)gridDim.x * blockDim.x;
  for (; i < n4; i += stride) {
    float4 v = reinterpret_cast<const float4*>(in)[i];
    ushort4 o = make_ushort4(f2bf(v.x), f2bf(v.y), f2bf(v.z), f2bf(v.w));
    reinterpret_cast<ushort4*>(out)[i] = o;
  }
}

// ---------------------------------------------------------------------------
// 256x256-tile, BK=64, 8-wave (2Mx4N), software-pipelined 4-window K-tile.
// Quadrants: W0:A0xB0 W1:A0xB1 W2:A1xB0 W3:A1xB1.
// Frags read in window w are consumed in window w+1 (LDS pipe overlaps MFMA):
//   W0 reads B1[t]; W1 reads A1[t]; W2 reads A0[t+1]; W3 reads B0[t+1].
// Stages run 5 windows ahead of their read:
//   W0 stages A1[t+1]; W1: A0[t+2]; W2: B0[t+2]; W3: B1[t+2].
// vmcnt(8) before each window-end barrier drains exactly the chunk the next
// window reads (FIFO-verified; tail 6/4/2/0). One barrier per window; every
// DMA target is >=3 windows after that region's last ds_read (reader drains
// its lgkm before the intervening MFMA, then >=1 barrier precedes the DMA).
// LDS row remap (A and B identical): lds row lr -> logical row/col
//   R = ((lr>>5)&3)*64 + (lr>>7)*32 + (lr&31)
// so each 128-row LDS half = the half-chunks {rows with (R&63)<32} etc.
// Swizzle (G4): byte ^= ((row&7)<<4), inverse-applied on the global source
// (linear LDS dest for global_load_lds) and on ds_read addresses (row&7==fr&7).
// TMODE=1: additionally write transposed bf16 output to Tout[z2][col][row].
// ---------------------------------------------------------------------------
template<int OUT_BF16, int HAS_BIAS, int TMODE>
__global__ __launch_bounds__(512, 2)
void gemm256(const ushort* __restrict__ A, const ushort* __restrict__ Bt,
             void* __restrict__ Cv, const float* __restrict__ bias,
             ushort* __restrict__ Tout,
             int M, int N, int K, float scale,
             long sA, long sB, long sC)
{
  __shared__ __align__(16) ushort As[2][16384];
  __shared__ __align__(16) ushort Bs[2][16384];

  const int t = threadIdx.x;
  const int z = blockIdx.z;
  const ushort* Ab = A + (long)z * sA;
  const ushort* Bb = Bt + (long)z * sB;
  const int tm = blockIdx.y * 256;
  const int tn = blockIdx.x * 256;

  const int l    = t & 63;
  const int w    = t >> 6;
  const int wrow = w >> 2;          // 0..1
  const int wcol = w & 3;           // 0..3
  const int fr   = l & 15;
  const int g    = l >> 4;          // 0..3
  const int aflip = (fr & 7) << 4;  // G4 swizzle XOR

  // ---- per-thread ds_read base pointers (offsets become ds imm) ----
  const int q0 = (g << 4) ^ aflip;
  const int q1 = (64 + (g << 4)) ^ aflip;
  const char* pA0 = (const char*)As + (wrow << 13) + (fr << 7) + q0;
  const char* pA1 = (const char*)As + (wrow << 13) + (fr << 7) + q1;
  const char* pB0 = (const char*)Bs + (wcol << 12) + (fr << 7) + q0;
  const char* pB1 = (const char*)Bs + (wcol << 12) + (fr << 7) + q1;

  // ldA/ldB with literal mi/ni/buf -> single vaddr + imm offset
  auto ldA = [&](int buf, int mi, int ks) -> short8 {
    const int off = (buf << 15) + ((mi >> 1 & 1) << 14) + ((mi >> 2) << 12) + ((mi & 1) << 11);
    return *(const short8*)((ks ? pA1 : pA0) + off);
  };
  auto ldB = [&](int buf, int ni, int ks) -> short8 {
    const int off = (buf << 15) + ((ni >> 1 & 1) << 14) + ((ni & 1) << 11);
    return *(const short8*)((ks ? pB1 : pB0) + off);
  };

  // ---- staging: one call = 512 thr x 16B = 8KB = 64 LDS rows; chunk=2 calls
  const long tmK = (long)tm * K;
  const long tnK = (long)tn * K;
  auto soff = [&](int j) {
    const int P  = (j << 13) + (t << 4);          // physical LDS byte
    const int L  = P ^ (((P >> 7) & 7) << 4);     // logical byte (involution)
    const int lr = L >> 7;
    const int kb = (L & 127) >> 1;
    return (((lr >> 5) & 3) * 64 + ((lr >> 7) << 5) + (lr & 31)) * K + kb;
  };
  const long ao0 = tmK + soff(0), ao1 = tmK + soff(1), ao2 = tmK + soff(2), ao3 = tmK + soff(3);
  const long bo0 = tnK + soff(0), bo1 = tnK + soff(1), bo2 = tnK + soff(2), bo3 = tnK + soff(3);
  const int t16 = t << 4;
  auto stgA = [&](int buf, int j, long go, int koff) {
    async16(Ab + go + koff, (char*)As + (buf << 15) + (j << 13) + t16);
  };
  auto stgB = [&](int buf, int j, long go, int koff) {
    async16(Bb + go + koff, (char*)Bs + (buf << 15) + (j << 13) + t16);
  };

  f32x4 acc[8][4];
#pragma unroll
  for (int i = 0; i < 8; ++i)
#pragma unroll
    for (int j = 0; j < 4; ++j) acc[i][j] = {0.f, 0.f, 0.f, 0.f};

  short8 a0[4][2], a1[4][2], b0[2][2], b1[2][2];
  constexpr int MI0[4] = {0, 1, 4, 5};
  constexpr int MI1[4] = {2, 3, 6, 7};

#define MFMA_Q(ASET, MIARR, BSET, NIOFF)                                        \
  __builtin_amdgcn_s_setprio(1);                                                \
  _Pragma("unroll") for (int ks = 0; ks < 2; ++ks)                              \
  _Pragma("unroll") for (int s = 0; s < 4; ++s)                                 \
  _Pragma("unroll") for (int ni = 0; ni < 2; ++ni)                              \
    acc[MIARR[s]][ni + NIOFF] = __builtin_amdgcn_mfma_f32_16x16x32_bf16(        \
        ASET[s][ks], BSET[ni][ks], acc[MIARR[s]][ni + NIOFF], 0, 0, 0);         \
  __builtin_amdgcn_s_setprio(0);

  const int NKT = K >> 6;  // = 16 here (>= 3 required by this schedule)

  // ---- prologue: stage A0[0],B0[0],B1[0],A1[0],A0[1],B0[1],B1[1] (14 calls)
  stgA(0, 0, ao0, 0);  stgA(0, 1, ao1, 0);     // A0[0]
  stgB(0, 0, bo0, 0);  stgB(0, 1, bo1, 0);     // B0[0]
  stgB(0, 2, bo2, 0);  stgB(0, 3, bo3, 0);     // B1[0]
  stgA(0, 2, ao2, 0);  stgA(0, 3, ao3, 0);     // A1[0]
  stgA(1, 0, ao0, 64); stgA(1, 1, ao1, 64);    // A0[1]
  stgB(1, 0, bo0, 64); stgB(1, 1, bo1, 64);    // B0[1]
  stgB(1, 2, bo2, 64); stgB(1, 3, bo3, 64);    // B1[1]
  VM(8);                                       // drain A0[0],B0[0],B1[0]
  BAR;

  // pre-reads: A0[0], B0[0] (consumed by W0[0]'s MFMA)
#pragma unroll
  for (int s = 0; s < 4; ++s) { a0[s][0] = ldA(0, MI0[s], 0); a0[s][1] = ldA(0, MI0[s], 1); }
#pragma unroll
  for (int ni = 0; ni < 2; ++ni) { b0[ni][0] = ldB(0, ni, 0); b0[ni][1] = ldB(0, ni, 1); }

#pragma unroll 2
  for (int kt = 0; kt < NKT; ++kt) {
    const int buf = kt & 1;
    const bool h1 = (kt + 1) < NKT;
    const bool h2 = (kt + 2) < NKT;
    const int k1 = (kt + 1) << 6;
    const int k2 = (kt + 2) << 6;

    // ---- W0: read B1[kt]; stage A1[kt+1]; MFMA A0xB0
#pragma unroll
    for (int ni = 0; ni < 2; ++ni) { b1[ni][0] = ldB(buf, ni + 2, 0); b1[ni][1] = ldB(buf, ni + 2, 1); }
    if (h1) { stgA(buf ^ 1, 2, ao2, k1); stgA(buf ^ 1, 3, ao3, k1); }
    SCHED0;
    MFMA_Q(a0, MI0, b0, 0);
    if (kt < NKT - 1) { VM(8); } else { VM(0); }   // drain A1[kt] for W1
    BAR;

    // ---- W1: read A1[kt]; stage A0[kt+2]; MFMA A0xB1
#pragma unroll
    for (int s = 0; s < 4; ++s) { a1[s][0] = ldA(buf, MI1[s], 0); a1[s][1] = ldA(buf, MI1[s], 1); }
    if (h2) { stgA(buf, 0, ao0, k2); stgA(buf, 1, ao1, k2); }
    SCHED0;
    MFMA_Q(a0, MI0, b1, 2);
    if (kt < NKT - 2) { VM(8); } else if (kt == NKT - 2) { VM(6); }  // drain A0[kt+1]
    BAR;

    // ---- W2: read A0[kt+1]; stage B0[kt+2]; MFMA A1xB0
    if (h1) {
#pragma unroll
      for (int s = 0; s < 4; ++s) { a0[s][0] = ldA(buf ^ 1, MI0[s], 0); a0[s][1] = ldA(buf ^ 1, MI0[s], 1); }
    }
    if (h2) { stgB(buf, 0, bo0, k2); stgB(buf, 1, bo1, k2); }
    SCHED0;
    MFMA_Q(a1, MI1, b0, 0);
    if (kt < NKT - 2) { VM(8); } else if (kt == NKT - 2) { VM(4); }  // drain B0[kt+1]
    BAR;

    // ---- W3: read B0[kt+1]; stage B1[kt+2]; MFMA A1xB1
    if (h1) {
#pragma unroll
      for (int ni = 0; ni < 2; ++ni) { b0[ni][0] = ldB(buf ^ 1, ni, 0); b0[ni][1] = ldB(buf ^ 1, ni, 1); }
    }
    if (h2) { stgB(buf, 2, bo2, k2); stgB(buf, 3, bo3, k2); }
    SCHED0;
    MFMA_Q(a1, MI1, b1, 2);
    if (kt < NKT - 2) { VM(8); } else if (kt == NKT - 2) { VM(2); }  // drain B1[kt+1]
    BAR;
  }
#undef MFMA_Q

  // --- epilogue: C/D layout col=lane&15, row=g*4+reg ---
  const int cr = g * 4;
#pragma unroll
  for (int mi = 0; mi < 8; ++mi) {
#pragma unroll
    for (int ni = 0; ni < 4; ++ni) {
      const int row = tm + wrow * 128 + mi * 16 + cr;
      const int col = tn + wcol * 64 + ni * 16 + fr;
      const float bv = HAS_BIAS ? bias[col] : 0.0f;
      float v[4];
#pragma unroll
      for (int r = 0; r < 4; ++r) v[r] = acc[mi][ni][r] * scale + bv;
#pragma unroll
      for (int r = 0; r < 4; ++r) {
        const long off = (long)z * sC + (long)(row + r) * N + col;
        if (OUT_BF16) ((ushort*)Cv)[off] = f2bf(v[r]);
        else          ((float*)Cv)[off]  = v[r];
      }
      if (TMODE) {  // transposed copy: Tout[z2][col][row..row+3], z2 = row>>10
        ushort4 o = make_ushort4(f2bf(v[0]), f2bf(v[1]), f2bf(v[2]), f2bf(v[3]));
        const long ti = ((long)(row >> 10) << 20) + ((long)col << 10) + (row & 1023);
        *(ushort4*)&Tout[ti] = o;
      }
    }
  }
}

// softmax over BATCH dim (axis=0): for each (q,k), normalize across 32 batches.
__global__ void softmax_b(ushort* __restrict__ sc) {
  const long SSl = (long)SEQ * SEQ;
  const long e = ((long)blockIdx.x * blockDim.x + threadIdx.x) * 4;
  if (e >= SSl) return;
  uint2 raw[BB];
#pragma unroll
  for (int b = 0; b < BB; ++b) raw[b] = *(const uint2*)&sc[b * SSl + e];
  float mx[4] = {-3.0e38f, -3.0e38f, -3.0e38f, -3.0e38f};
#pragma unroll
  for (int b = 0; b < BB; ++b) {
    const uint lo = raw[b].x, hi = raw[b].y;
    mx[0] = fmaxf(mx[0], bf2f((ushort)(lo & 0xffffu)));
    mx[1] = fmaxf(mx[1], bf2f((ushort)(lo >> 16)));
    mx[2] = fmaxf(mx[2], bf2f((ushort)(hi & 0xffffu)));
    mx[3] = fmaxf(mx[3], bf2f((ushort)(hi >> 16)));
  }
  float sum[4] = {0.f, 0.f, 0.f, 0.f};
#pragma unroll
  for (int b = 0; b < BB; ++b) {
    const uint lo = raw[b].x, hi = raw[b].y;
    const float x0 = __expf(bf2f((ushort)(lo & 0xffffu)) - mx[0]);
    const float x1 = __expf(bf2f((ushort)(lo >> 16))     - mx[1]);
    const float x2 = __expf(bf2f((ushort)(hi & 0xffffu)) - mx[2]);
    const float x3 = __expf(bf2f((ushort)(hi >> 16))     - mx[3]);
    sum[0] += x0; sum[1] += x1; sum[2] += x2; sum[3] += x3;
    raw[b].x = (uint)f2bf(x0) | ((uint)f2bf(x1) << 16);
    raw[b].y = (uint)f2bf(x2) | ((uint)f2bf(x3) << 16);
  }
  const float r0 = 1.0f / sum[0], r1 = 1.0f / sum[1];
  const float r2 = 1.0f / sum[2], r3 = 1.0f / sum[3];
#pragma unroll
  for (int b = 0; b < BB; ++b) {
    const uint lo = raw[b].x, hi = raw[b].y;
    const uint o0 = f2bf(bf2f((ushort)(lo & 0xffffu)) * r0);
    const uint o1 = f2bf(bf2f((ushort)(lo >> 16))     * r1);
    const uint o2 = f2bf(bf2f((ushort)(hi & 0xffffu)) * r2);
    const uint o3 = f2bf(bf2f((ushort)(hi >> 16))     * r3);
    uint2 o; o.x = o0 | (o1 << 16); o.y = o2 | (o3 << 16);
    *(uint2*)&sc[b * SSl + e] = o;
  }
}

extern "C" void kernel_launch(void* const* d_in, const int* in_sizes, int n_in,
                              void* d_out, int out_size, void* d_ws, size_t ws_size,
                              hipStream_t stream) {
  const float* text = (const float*)d_in[0];
  const float* W    = (const float*)d_in[1];
  const float* bias = (const float*)d_in[2];
  float* out = (float*)d_out;

  const long nTxt = (long)BB * SEQ * DIM;   // 33,554,432
  const long nW   = (long)DIM * DIM;        // 1,048,576
  const long SSl  = (long)SEQ * SEQ;        // per-batch score elems

  char* ws = (char*)d_ws;
  ushort* qkv   = (ushort*)ws;                 // 64MB bf16 qkv [B][S][D]
  ushort* qkvT  = (ushort*)(ws + nTxt * 2);    // 64MB bf16 qkv^T [B][D][S]
  ushort* sc    = (ushort*)(ws + nTxt * 4);    // 64MB: text_bf16, then scores/attn
  ushort* textb = sc;                          // alias (text_bf16 dead after GEMM1)
  ushort* Wb    = (ushort*)(ws + nTxt * 6);    // 2MB bf16 W [D][D]
  if (ws_size < (size_t)(nTxt * 6 + nW * 2)) return;  // insufficient scratch

  // 1. convert inputs to bf16
  cvt_kernel<<<2048, 256, 0, stream>>>(text, textb, nTxt / 4);
  cvt_kernel<<<256, 256, 0, stream>>>(W, Wb, nW / 4);
  // 2. qkv = text @ W.T + b  (M=32768,N=1024,K=1024); also writes qkvT fused
  gemm256<1, 1, 1><<<dim3(4, 128, 1), 512, 0, stream>>>(
      textb, Wb, qkv, bias, qkvT, BB * SEQ, DIM, DIM, 1.0f, 0, 0, 0);
  // 3. scores[b] = qkv[b] @ qkv[b]^T / sqrt(D), bf16 out
  gemm256<1, 0, 0><<<dim3(4, 4, BB), 512, 0, stream>>>(
      qkv, qkv, sc, nullptr, nullptr, SEQ, SEQ, DIM, 0.03125f, SSl, SSl, SSl);
  // 4. softmax over batch dim (in-place)
  softmax_b<<<1024, 256, 0, stream>>>(sc);
  // 5. out[b] = attn[b] @ qkv[b]  (B operand via qkvT), fp32 out
  gemm256<0, 0, 0><<<dim3(4, 4, BB), 512, 0, stream>>>(
      sc, qkvT, out, nullptr, nullptr, SEQ, DIM, SEQ, 1.0f, SSl, SSl, SSl);
}